// Round 1
// baseline (1506.261 us; speedup 1.0000x reference)
//
#include <hip/hip_runtime.h>
#include <hip/hip_bf16.h>

// ---------------------------------------------------------------------------
// CompGCN layer, restructured:
//   scatter(x[src]*rel[et]*norm) -> acc_in/acc_out   (linearity of matmul)
//   h = (acc_in@in_w + acc_out@out_w + (x*loop_rel)@loop_w)/3 + bias
//   BN(train) + ReLU ; out_rel = rel @ w_rel
// ---------------------------------------------------------------------------

__global__ __launch_bounds__(256) void edge_scatter_kernel(
    const float* __restrict__ x,
    const float* __restrict__ rel,
    const float* __restrict__ edge_norm,
    const int* __restrict__ edge_type,
    const int* __restrict__ src,
    const int* __restrict__ dst,
    float* __restrict__ acc_in,
    float* __restrict__ acc_out,
    int E)
{
    int tid = blockIdx.x * 256 + threadIdx.x;
    int edge = tid >> 5;              // 32 threads per edge
    if (edge >= E) return;
    int f0 = (tid & 31) << 2;         // feature offset 0,4,...,124

    int s = src[edge];
    int d = dst[edge];
    int t = edge_type[edge];
    float n = edge_norm[edge];

    const float4 xv = *reinterpret_cast<const float4*>(x + (size_t)s * 128 + f0);
    const float4 rv = *reinterpret_cast<const float4*>(rel + (size_t)t * 128 + f0);

    int half = E >> 1;
    float* accp = (edge < half ? acc_in : acc_out) + (size_t)d * 128 + f0;
    atomicAdd(accp + 0, xv.x * rv.x * n);
    atomicAdd(accp + 1, xv.y * rv.y * n);
    atomicAdd(accp + 2, xv.z * rv.z * n);
    atomicAdd(accp + 3, xv.w * rv.w * n);
}

#define GEMM_ROWS 16

__global__ __launch_bounds__(256) void fused_gemm_kernel(
    const float* __restrict__ acc_in,
    const float* __restrict__ acc_out,
    const float* __restrict__ x,
    const float* __restrict__ in_w,
    const float* __restrict__ out_w,
    const float* __restrict__ loop_w,
    const float* __restrict__ loop_rel,
    const float* __restrict__ bias,
    float* __restrict__ h,
    int V)
{
    __shared__ float a_tile[GEMM_ROWS][128];

    int col = threadIdx.x & 127;
    int rg  = threadIdx.x >> 7;           // 0 or 1
    int row0 = blockIdx.x * GEMM_ROWS;

    float acc[8];
#pragma unroll
    for (int r = 0; r < 8; ++r) acc[r] = 0.f;

    const float* mats[3] = { acc_in, acc_out, x };
    const float* wgts[3] = { in_w, out_w, loop_w };

    for (int t = 0; t < 3; ++t) {
        __syncthreads();
        // stage GEMM_ROWS x 128 A-tile
        for (int i = threadIdx.x; i < GEMM_ROWS * 128; i += 256) {
            int r = i >> 7, c = i & 127;
            float v = mats[t][(size_t)(row0 + r) * 128 + c];
            if (t == 2) v *= loop_rel[c];
            a_tile[r][c] = v;
        }
        __syncthreads();
        const float* W = wgts[t];
        for (int k = 0; k < 128; ++k) {
            float w = W[k * 128 + col];
#pragma unroll
            for (int r = 0; r < 8; ++r)
                acc[r] += a_tile[rg + 2 * r][k] * w;
        }
    }

    float b = bias[col];
#pragma unroll
    for (int r = 0; r < 8; ++r) {
        int row = row0 + rg + 2 * r;
        h[(size_t)row * 128 + col] = acc[r] * (1.f / 3.f) + b;
    }
}

__global__ __launch_bounds__(256) void bn_stats_kernel(
    const float* __restrict__ h,
    float* __restrict__ stats,   // [0:128] sum, [128:256] sumsq
    int V)
{
    int col = threadIdx.x & 127;
    int rg  = threadIdx.x >> 7;
    float s = 0.f, s2 = 0.f;
    for (int row = blockIdx.x * 2 + rg; row < V; row += gridDim.x * 2) {
        float v = h[(size_t)row * 128 + col];
        s  += v;
        s2 += v * v;
    }
    __shared__ float red[256];
    red[threadIdx.x] = s;
    __syncthreads();
    float s_sum = (rg == 0) ? (s + red[threadIdx.x + 128]) : 0.f;
    __syncthreads();
    red[threadIdx.x] = s2;
    __syncthreads();
    if (rg == 0) {
        float s2_sum = s2 + red[threadIdx.x + 128];
        atomicAdd(&stats[col], s_sum);
        atomicAdd(&stats[128 + col], s2_sum);
    }
}

__global__ __launch_bounds__(256) void bn_apply_kernel(
    float* __restrict__ h,
    const float* __restrict__ stats,
    const float* __restrict__ gamma,
    const float* __restrict__ beta,
    int V)
{
    int col = threadIdx.x & 127;
    int rg  = threadIdx.x >> 7;
    float inv_v = 1.f / (float)V;
    float mean = stats[col] * inv_v;
    float var  = stats[128 + col] * inv_v - mean * mean;
    float sc = rsqrtf(var + 1e-5f) * gamma[col];
    float sh = beta[col] - mean * sc;
    for (int row = blockIdx.x * 2 + rg; row < V; row += gridDim.x * 2) {
        float v = h[(size_t)row * 128 + col];
        v = v * sc + sh;
        h[(size_t)row * 128 + col] = v > 0.f ? v : 0.f;
    }
}

__global__ __launch_bounds__(256) void rel_gemm_kernel(
    const float* __restrict__ rel,
    const float* __restrict__ w_rel,
    float* __restrict__ out_rel,
    int R)
{
    int col = threadIdx.x & 127;
    int row = blockIdx.x * 2 + (threadIdx.x >> 7);
    if (row >= R) return;
    float acc = 0.f;
    for (int k = 0; k < 128; ++k)
        acc += rel[row * 128 + k] * w_rel[k * 128 + col];
    out_rel[row * 128 + col] = acc;
}

extern "C" void kernel_launch(void* const* d_in, const int* in_sizes, int n_in,
                              void* d_out, int out_size, void* d_ws, size_t ws_size,
                              hipStream_t stream)
{
    const float* x         = (const float*)d_in[0];
    const float* rel_repr  = (const float*)d_in[1];
    const float* edge_norm = (const float*)d_in[2];
    const float* in_w      = (const float*)d_in[3];
    const float* out_w     = (const float*)d_in[4];
    const float* loop_w    = (const float*)d_in[5];
    const float* w_rel     = (const float*)d_in[6];
    const float* loop_rel  = (const float*)d_in[7];
    const float* bias      = (const float*)d_in[8];
    const float* bn_gamma  = (const float*)d_in[9];
    const float* bn_beta   = (const float*)d_in[10];
    const int* edge_type   = (const int*)d_in[11];
    const int* src         = (const int*)d_in[12];
    const int* dst         = (const int*)d_in[13];

    const int V = in_sizes[0] / 128;     // 50000
    const int E = in_sizes[2];           // 800000
    const int R = in_sizes[1] / 128;     // 200

    float* h       = (float*)d_out;              // [V,128]
    float* out_rel = h + (size_t)V * 128;        // [R,128]

    float* acc_in  = (float*)d_ws;               // [V,128]
    float* acc_out = acc_in + (size_t)V * 128;   // [V,128]
    float* stats   = acc_out + (size_t)V * 128;  // [256]

    // zero accumulators + stats (ws is poisoned; must re-init every call)
    size_t zero_bytes = ((size_t)2 * V * 128 + 256) * sizeof(float);
    hipMemsetAsync(d_ws, 0, zero_bytes, stream);

    // 1. edge scatter: 32 threads/edge
    {
        long long total = (long long)E * 32;
        int blocks = (int)((total + 255) / 256);
        edge_scatter_kernel<<<blocks, 256, 0, stream>>>(
            x, rel_repr, edge_norm, edge_type, src, dst, acc_in, acc_out, E);
    }

    // 2. fused 3-way GEMM + bias + /3
    {
        int blocks = (V + GEMM_ROWS - 1) / GEMM_ROWS;   // 3125
        fused_gemm_kernel<<<blocks, 256, 0, stream>>>(
            acc_in, acc_out, x, in_w, out_w, loop_w, loop_rel, bias, h, V);
    }

    // 3. BN stats
    bn_stats_kernel<<<512, 256, 0, stream>>>(h, stats, V);

    // 4. BN apply + ReLU (in place)
    bn_apply_kernel<<<1024, 256, 0, stream>>>(h, stats, bn_gamma, bn_beta, V);

    // 5. out_rel = rel @ w_rel
    rel_gemm_kernel<<<(R + 1) / 2, 256, 0, stream>>>(rel_repr, w_rel, out_rel, R);
}

// Round 2
// 527.350 us; speedup vs baseline: 2.8563x; 2.8563x over previous
//
#include <hip/hip_runtime.h>
#include <hip/hip_bf16.h>

// ---------------------------------------------------------------------------
// CompGCN layer:
//   CSR-by-(dst,half) counting sort, then per-bucket register aggregation
//   (kills the 102M feature atomics that dominated round 0),
//   then h = (acc_in@in_w + acc_out@out_w + (x*loop_rel)@loop_w)/3 + bias,
//   BN(train) + ReLU ; out_rel = rel @ w_rel
// ---------------------------------------------------------------------------

__global__ __launch_bounds__(256) void hist_kernel(
    const int* __restrict__ dst, int* __restrict__ cnt, int E, int V)
{
    int e = blockIdx.x * 256 + threadIdx.x;
    if (e >= E) return;
    int key = dst[e] + (e < (E >> 1) ? 0 : V);
    atomicAdd(&cnt[key], 1);
}

__global__ __launch_bounds__(1024) void scan_kernel(
    const int* __restrict__ cnt, int* __restrict__ off, int* __restrict__ cur,
    int N, int E)
{
    __shared__ int partials[1024];
    int t = threadIdx.x;
    int chunk = (N + 1023) >> 10;
    int lo = t * chunk;
    int hi = min(lo + chunk, N);
    int sum = 0;
    for (int i = lo; i < hi; ++i) sum += cnt[i];
    partials[t] = sum;
    __syncthreads();
    // Hillis-Steele inclusive scan
    for (int s = 1; s < 1024; s <<= 1) {
        int v = (t >= s) ? partials[t - s] : 0;
        __syncthreads();
        partials[t] += v;
        __syncthreads();
    }
    int run = (t == 0) ? 0 : partials[t - 1];
    for (int i = lo; i < hi; ++i) {
        off[i] = run;
        cur[i] = run;
        run += cnt[i];
    }
    if (t == 1023) off[N] = E;
}

// scatter pre-gathered payload into sorted position
__global__ __launch_bounds__(256) void rank_kernel(
    const int* __restrict__ dst,
    const int* __restrict__ src,
    const int* __restrict__ edge_type,
    const float* __restrict__ edge_norm,
    int* __restrict__ cur,
    unsigned* __restrict__ pay_st,   // (src<<16)|type
    float* __restrict__ pay_n,
    int E, int V)
{
    int e = blockIdx.x * 256 + threadIdx.x;
    if (e >= E) return;
    int key = dst[e] + (e < (E >> 1) ? 0 : V);
    int pos = atomicAdd(&cur[key], 1);
    pay_st[pos] = ((unsigned)src[e] << 16) | (unsigned)edge_type[e];
    pay_n[pos]  = edge_norm[e];
}

// one 32-lane group per bucket; plain stores, no feature atomics
__global__ __launch_bounds__(256) void aggregate_kernel(
    const float* __restrict__ x,
    const float* __restrict__ rel,
    const unsigned* __restrict__ pay_st,
    const float* __restrict__ pay_n,
    const int* __restrict__ off,
    float* __restrict__ acc,         // [2V,128] = [acc_in ; acc_out]
    int NK)
{
    int gid = (blockIdx.x * 256 + threadIdx.x) >> 5;
    if (gid >= NK) return;
    int lane = threadIdx.x & 31;
    int f0 = lane << 2;

    int beg = off[gid], end = off[gid + 1];
    float4 a = make_float4(0.f, 0.f, 0.f, 0.f);

    for (int base = beg; base < end; base += 32) {
        int j = base + lane;
        unsigned p = 0; float n = 0.f;
        if (j < end) { p = pay_st[j]; n = pay_n[j]; }
        int m = min(32, end - base);
        for (int q = 0; q < m; ++q) {
            unsigned pq = __shfl(p, q, 32);
            float nq = __shfl(n, q, 32);
            int s = (int)(pq >> 16);
            int t = (int)(pq & 0xffffu);
            const float4 xv = *reinterpret_cast<const float4*>(x + (size_t)s * 128 + f0);
            const float4 rv = *reinterpret_cast<const float4*>(rel + (size_t)t * 128 + f0);
            a.x += xv.x * rv.x * nq;
            a.y += xv.y * rv.y * nq;
            a.z += xv.z * rv.z * nq;
            a.w += xv.w * rv.w * nq;
        }
    }
    *reinterpret_cast<float4*>(acc + (size_t)gid * 128 + f0) = a;
}

#define GEMM_ROWS 16

__global__ __launch_bounds__(256) void fused_gemm_kernel(
    const float* __restrict__ acc_in,
    const float* __restrict__ acc_out,
    const float* __restrict__ x,
    const float* __restrict__ in_w,
    const float* __restrict__ out_w,
    const float* __restrict__ loop_w,
    const float* __restrict__ loop_rel,
    const float* __restrict__ bias,
    float* __restrict__ h,
    int V)
{
    __shared__ float a_tile[GEMM_ROWS][128];

    int col = threadIdx.x & 127;
    int rg  = threadIdx.x >> 7;           // 0 or 1
    int row0 = blockIdx.x * GEMM_ROWS;

    float acc[8];
#pragma unroll
    for (int r = 0; r < 8; ++r) acc[r] = 0.f;

    const float* mats[3] = { acc_in, acc_out, x };
    const float* wgts[3] = { in_w, out_w, loop_w };

    for (int t = 0; t < 3; ++t) {
        __syncthreads();
        for (int i = threadIdx.x; i < GEMM_ROWS * 128; i += 256) {
            int r = i >> 7, c = i & 127;
            float v = mats[t][(size_t)(row0 + r) * 128 + c];
            if (t == 2) v *= loop_rel[c];
            a_tile[r][c] = v;
        }
        __syncthreads();
        const float* W = wgts[t];
        for (int k = 0; k < 128; ++k) {
            float w = W[k * 128 + col];
#pragma unroll
            for (int r = 0; r < 8; ++r)
                acc[r] += a_tile[rg + 2 * r][k] * w;
        }
    }

    float b = bias[col];
#pragma unroll
    for (int r = 0; r < 8; ++r) {
        int row = row0 + rg + 2 * r;
        h[(size_t)row * 128 + col] = acc[r] * (1.f / 3.f) + b;
    }
}

__global__ __launch_bounds__(256) void bn_stats_kernel(
    const float* __restrict__ h,
    float* __restrict__ stats,   // [0:128] sum, [128:256] sumsq
    int V)
{
    int col = threadIdx.x & 127;
    int rg  = threadIdx.x >> 7;
    float s = 0.f, s2 = 0.f;
    for (int row = blockIdx.x * 2 + rg; row < V; row += gridDim.x * 2) {
        float v = h[(size_t)row * 128 + col];
        s  += v;
        s2 += v * v;
    }
    __shared__ float red[256];
    red[threadIdx.x] = s;
    __syncthreads();
    float s_sum = (rg == 0) ? (s + red[threadIdx.x + 128]) : 0.f;
    __syncthreads();
    red[threadIdx.x] = s2;
    __syncthreads();
    if (rg == 0) {
        float s2_sum = s2 + red[threadIdx.x + 128];
        atomicAdd(&stats[col], s_sum);
        atomicAdd(&stats[128 + col], s2_sum);
    }
}

__global__ __launch_bounds__(256) void bn_apply_kernel(
    float* __restrict__ h,
    const float* __restrict__ stats,
    const float* __restrict__ gamma,
    const float* __restrict__ beta,
    int V)
{
    int col = threadIdx.x & 127;
    int rg  = threadIdx.x >> 7;
    float inv_v = 1.f / (float)V;
    float mean = stats[col] * inv_v;
    float var  = stats[128 + col] * inv_v - mean * mean;
    float sc = rsqrtf(var + 1e-5f) * gamma[col];
    float sh = beta[col] - mean * sc;
    for (int row = blockIdx.x * 2 + rg; row < V; row += gridDim.x * 2) {
        float v = h[(size_t)row * 128 + col];
        v = v * sc + sh;
        h[(size_t)row * 128 + col] = v > 0.f ? v : 0.f;
    }
}

__global__ __launch_bounds__(256) void rel_gemm_kernel(
    const float* __restrict__ rel,
    const float* __restrict__ w_rel,
    float* __restrict__ out_rel,
    int R)
{
    int col = threadIdx.x & 127;
    int row = blockIdx.x * 2 + (threadIdx.x >> 7);
    if (row >= R) return;
    float acc = 0.f;
    for (int k = 0; k < 128; ++k)
        acc += rel[row * 128 + k] * w_rel[k * 128 + col];
    out_rel[row * 128 + col] = acc;
}

extern "C" void kernel_launch(void* const* d_in, const int* in_sizes, int n_in,
                              void* d_out, int out_size, void* d_ws, size_t ws_size,
                              hipStream_t stream)
{
    const float* x         = (const float*)d_in[0];
    const float* rel_repr  = (const float*)d_in[1];
    const float* edge_norm = (const float*)d_in[2];
    const float* in_w      = (const float*)d_in[3];
    const float* out_w     = (const float*)d_in[4];
    const float* loop_w    = (const float*)d_in[5];
    const float* w_rel     = (const float*)d_in[6];
    const float* loop_rel  = (const float*)d_in[7];
    const float* bias      = (const float*)d_in[8];
    const float* bn_gamma  = (const float*)d_in[9];
    const float* bn_beta   = (const float*)d_in[10];
    const int* edge_type   = (const int*)d_in[11];
    const int* src         = (const int*)d_in[12];
    const int* dst         = (const int*)d_in[13];

    const int V = in_sizes[0] / 128;     // 50000
    const int E = in_sizes[2];           // 800000
    const int R = in_sizes[1] / 128;     // 200
    const int NK = 2 * V;                // buckets: [dst(in) ; dst(out)]

    float* h       = (float*)d_out;              // [V,128]
    float* out_rel = h + (size_t)V * 128;        // [R,128]

    // workspace layout
    float*    acc    = (float*)d_ws;                       // [2V,128]
    float*    stats  = acc + (size_t)NK * 128;             // [256]
    int*      cnt    = (int*)(stats + 256);                // [2V]
    int*      off    = cnt + NK;                           // [2V+1]
    int*      cur    = off + NK + 1;                       // [2V]
    unsigned* pay_st = (unsigned*)(cur + NK);              // [E]
    float*    pay_n  = (float*)(pay_st + E);               // [E]

    // zero stats + cnt only (adjacent); acc is fully written by aggregate
    hipMemsetAsync(stats, 0, (256 + (size_t)NK) * sizeof(int), stream);

    int eb = (E + 255) / 256;
    hist_kernel<<<eb, 256, 0, stream>>>(dst, cnt, E, V);
    scan_kernel<<<1, 1024, 0, stream>>>(cnt, off, cur, NK, E);
    rank_kernel<<<eb, 256, 0, stream>>>(dst, src, edge_type, edge_norm,
                                        cur, pay_st, pay_n, E, V);
    aggregate_kernel<<<(NK * 32 + 255) / 256, 256, 0, stream>>>(
        x, rel_repr, pay_st, pay_n, off, acc, NK);

    // fused 3-way GEMM + bias + /3
    fused_gemm_kernel<<<(V + GEMM_ROWS - 1) / GEMM_ROWS, 256, 0, stream>>>(
        acc /*acc_in*/, acc + (size_t)V * 128 /*acc_out*/, x,
        in_w, out_w, loop_w, loop_rel, bias, h, V);

    bn_stats_kernel<<<512, 256, 0, stream>>>(h, stats, V);
    bn_apply_kernel<<<1024, 256, 0, stream>>>(h, stats, bn_gamma, bn_beta, V);
    rel_gemm_kernel<<<(R + 1) / 2, 256, 0, stream>>>(rel_repr, w_rel, out_rel, R);
}

// Round 3
// 314.905 us; speedup vs baseline: 4.7832x; 1.6746x over previous
//
#include <hip/hip_runtime.h>
#include <hip/hip_bf16.h>

// ---------------------------------------------------------------------------
// CompGCN layer:
//   CSR-by-(dst,half) counting sort (3-phase parallel scan), per-bucket
//   register aggregation, fused 3-way GEMM + bias + /3, BN(train) + ReLU,
//   out_rel = rel @ w_rel.
// ---------------------------------------------------------------------------

#define SCAN_BLOCK 256

__global__ __launch_bounds__(256) void hist_kernel(
    const int* __restrict__ dst, int* __restrict__ cnt, int E, int V)
{
    int e = blockIdx.x * 256 + threadIdx.x;
    if (e >= E) return;
    int key = dst[e] + (e < (E >> 1) ? 0 : V);
    atomicAdd(&cnt[key], 1);
}

// phase 1: per-block sums of 256 counts
__global__ __launch_bounds__(SCAN_BLOCK) void scan_partial_kernel(
    const int* __restrict__ cnt, int* __restrict__ partials, int N)
{
    __shared__ int red[SCAN_BLOCK];
    int i = blockIdx.x * SCAN_BLOCK + threadIdx.x;
    red[threadIdx.x] = (i < N) ? cnt[i] : 0;
    __syncthreads();
    for (int s = SCAN_BLOCK / 2; s > 0; s >>= 1) {
        if (threadIdx.x < s) red[threadIdx.x] += red[threadIdx.x + s];
        __syncthreads();
    }
    if (threadIdx.x == 0) partials[blockIdx.x] = red[0];
}

// phase 2: one block scans the block sums -> exclusive block offsets
__global__ __launch_bounds__(1024) void scan_top_kernel(
    int* __restrict__ partials, int NB)
{
    __shared__ int sh[1024];
    int t = threadIdx.x;
    sh[t] = (t < NB) ? partials[t] : 0;
    __syncthreads();
    for (int s = 1; s < 1024; s <<= 1) {
        int v = (t >= s) ? sh[t - s] : 0;
        __syncthreads();
        sh[t] += v;
        __syncthreads();
    }
    if (t < NB) partials[t] = (t == 0) ? 0 : sh[t - 1];
}

// phase 3: block-local scan + block offset -> off/cur
__global__ __launch_bounds__(SCAN_BLOCK) void scan_final_kernel(
    const int* __restrict__ cnt, const int* __restrict__ partials,
    int* __restrict__ off, int* __restrict__ cur, int N, int E)
{
    __shared__ int sh[SCAN_BLOCK];
    int i = blockIdx.x * SCAN_BLOCK + threadIdx.x;
    int t = threadIdx.x;
    int v = (i < N) ? cnt[i] : 0;
    sh[t] = v;
    __syncthreads();
    for (int s = 1; s < SCAN_BLOCK; s <<= 1) {
        int u = (t >= s) ? sh[t - s] : 0;
        __syncthreads();
        sh[t] += u;
        __syncthreads();
    }
    int excl = partials[blockIdx.x] + sh[t] - v;
    if (i < N) { off[i] = excl; cur[i] = excl; }
    if (i == 0) off[N] = E;
}

// scatter pre-gathered payload into sorted position
__global__ __launch_bounds__(256) void rank_kernel(
    const int* __restrict__ dst,
    const int* __restrict__ src,
    const int* __restrict__ edge_type,
    const float* __restrict__ edge_norm,
    int* __restrict__ cur,
    unsigned* __restrict__ pay_st,   // (src<<16)|type
    float* __restrict__ pay_n,
    int E, int V)
{
    int e = blockIdx.x * 256 + threadIdx.x;
    if (e >= E) return;
    int key = dst[e] + (e < (E >> 1) ? 0 : V);
    int pos = atomicAdd(&cur[key], 1);
    pay_st[pos] = ((unsigned)src[e] << 16) | (unsigned)edge_type[e];
    pay_n[pos]  = edge_norm[e];
}

// one 32-lane group per bucket; plain stores, no feature atomics
__global__ __launch_bounds__(256) void aggregate_kernel(
    const float* __restrict__ x,
    const float* __restrict__ rel,
    const unsigned* __restrict__ pay_st,
    const float* __restrict__ pay_n,
    const int* __restrict__ off,
    float* __restrict__ acc,         // [2V,128] = [acc_in ; acc_out]
    int NK)
{
    int gid = (blockIdx.x * 256 + threadIdx.x) >> 5;
    if (gid >= NK) return;
    int lane = threadIdx.x & 31;
    int f0 = lane << 2;

    int beg = off[gid], end = off[gid + 1];
    float4 a = make_float4(0.f, 0.f, 0.f, 0.f);

    for (int base = beg; base < end; base += 32) {
        int j = base + lane;
        unsigned p = 0; float n = 0.f;
        if (j < end) { p = pay_st[j]; n = pay_n[j]; }
        int m = min(32, end - base);
        for (int q = 0; q < m; ++q) {
            unsigned pq = __shfl(p, q, 32);
            float nq = __shfl(n, q, 32);
            int s = (int)(pq >> 16);
            int t = (int)(pq & 0xffffu);
            const float4 xv = *reinterpret_cast<const float4*>(x + (size_t)s * 128 + f0);
            const float4 rv = *reinterpret_cast<const float4*>(rel + (size_t)t * 128 + f0);
            a.x += xv.x * rv.x * nq;
            a.y += xv.y * rv.y * nq;
            a.z += xv.z * rv.z * nq;
            a.w += xv.w * rv.w * nq;
        }
    }
    *reinterpret_cast<float4*>(acc + (size_t)gid * 128 + f0) = a;
}

#define GEMM_ROWS 16

__global__ __launch_bounds__(256) void fused_gemm_kernel(
    const float* __restrict__ acc_in,
    const float* __restrict__ acc_out,
    const float* __restrict__ x,
    const float* __restrict__ in_w,
    const float* __restrict__ out_w,
    const float* __restrict__ loop_w,
    const float* __restrict__ loop_rel,
    const float* __restrict__ bias,
    float* __restrict__ h,
    int V)
{
    __shared__ float a_tile[GEMM_ROWS][128];

    int col = threadIdx.x & 127;
    int rg  = threadIdx.x >> 7;           // 0 or 1
    int row0 = blockIdx.x * GEMM_ROWS;

    float acc[8];
#pragma unroll
    for (int r = 0; r < 8; ++r) acc[r] = 0.f;

    const float* mats[3] = { acc_in, acc_out, x };
    const float* wgts[3] = { in_w, out_w, loop_w };

    for (int t = 0; t < 3; ++t) {
        __syncthreads();
        for (int i = threadIdx.x; i < GEMM_ROWS * 128; i += 256) {
            int r = i >> 7, c = i & 127;
            float v = mats[t][(size_t)(row0 + r) * 128 + c];
            if (t == 2) v *= loop_rel[c];
            a_tile[r][c] = v;
        }
        __syncthreads();
        const float* W = wgts[t];
        for (int k = 0; k < 128; ++k) {
            float w = W[k * 128 + col];
#pragma unroll
            for (int r = 0; r < 8; ++r)
                acc[r] += a_tile[rg + 2 * r][k] * w;
        }
    }

    float b = bias[col];
#pragma unroll
    for (int r = 0; r < 8; ++r) {
        int row = row0 + rg + 2 * r;
        h[(size_t)row * 128 + col] = acc[r] * (1.f / 3.f) + b;
    }
}

__global__ __launch_bounds__(256) void bn_stats_kernel(
    const float* __restrict__ h,
    float* __restrict__ stats,   // [0:128] sum, [128:256] sumsq
    int V)
{
    int col = threadIdx.x & 127;
    int rg  = threadIdx.x >> 7;
    float s = 0.f, s2 = 0.f;
    for (int row = blockIdx.x * 2 + rg; row < V; row += gridDim.x * 2) {
        float v = h[(size_t)row * 128 + col];
        s  += v;
        s2 += v * v;
    }
    __shared__ float red[256];
    red[threadIdx.x] = s;
    __syncthreads();
    float s_sum = (rg == 0) ? (s + red[threadIdx.x + 128]) : 0.f;
    __syncthreads();
    red[threadIdx.x] = s2;
    __syncthreads();
    if (rg == 0) {
        float s2_sum = s2 + red[threadIdx.x + 128];
        atomicAdd(&stats[col], s_sum);
        atomicAdd(&stats[128 + col], s2_sum);
    }
}

__global__ __launch_bounds__(256) void bn_apply_kernel(
    float* __restrict__ h,
    const float* __restrict__ stats,
    const float* __restrict__ gamma,
    const float* __restrict__ beta,
    int V)
{
    int col = threadIdx.x & 127;
    int rg  = threadIdx.x >> 7;
    float inv_v = 1.f / (float)V;
    float mean = stats[col] * inv_v;
    float var  = stats[128 + col] * inv_v - mean * mean;
    float sc = rsqrtf(var + 1e-5f) * gamma[col];
    float sh = beta[col] - mean * sc;
    for (int row = blockIdx.x * 2 + rg; row < V; row += gridDim.x * 2) {
        float v = h[(size_t)row * 128 + col];
        v = v * sc + sh;
        h[(size_t)row * 128 + col] = v > 0.f ? v : 0.f;
    }
}

__global__ __launch_bounds__(256) void rel_gemm_kernel(
    const float* __restrict__ rel,
    const float* __restrict__ w_rel,
    float* __restrict__ out_rel,
    int R)
{
    int col = threadIdx.x & 127;
    int row = blockIdx.x * 2 + (threadIdx.x >> 7);
    if (row >= R) return;
    float acc = 0.f;
    for (int k = 0; k < 128; ++k)
        acc += rel[row * 128 + k] * w_rel[k * 128 + col];
    out_rel[row * 128 + col] = acc;
}

extern "C" void kernel_launch(void* const* d_in, const int* in_sizes, int n_in,
                              void* d_out, int out_size, void* d_ws, size_t ws_size,
                              hipStream_t stream)
{
    const float* x         = (const float*)d_in[0];
    const float* rel_repr  = (const float*)d_in[1];
    const float* edge_norm = (const float*)d_in[2];
    const float* in_w      = (const float*)d_in[3];
    const float* out_w     = (const float*)d_in[4];
    const float* loop_w    = (const float*)d_in[5];
    const float* w_rel     = (const float*)d_in[6];
    const float* loop_rel  = (const float*)d_in[7];
    const float* bias      = (const float*)d_in[8];
    const float* bn_gamma  = (const float*)d_in[9];
    const float* bn_beta   = (const float*)d_in[10];
    const int* edge_type   = (const int*)d_in[11];
    const int* src         = (const int*)d_in[12];
    const int* dst         = (const int*)d_in[13];

    const int V = in_sizes[0] / 128;     // 50000
    const int E = in_sizes[2];           // 800000
    const int R = in_sizes[1] / 128;     // 200
    const int NK = 2 * V;                // buckets: [dst(in) ; dst(out)]
    const int NB = (NK + SCAN_BLOCK - 1) / SCAN_BLOCK;   // scan blocks (391)

    float* h       = (float*)d_out;              // [V,128]
    float* out_rel = h + (size_t)V * 128;        // [R,128]

    // workspace layout
    float*    acc      = (float*)d_ws;                     // [2V,128]
    float*    stats    = acc + (size_t)NK * 128;           // [256]
    int*      cnt      = (int*)(stats + 256);              // [2V]
    int*      off      = cnt + NK;                         // [2V+1]
    int*      cur      = off + NK + 1;                     // [2V]
    int*      partials = cur + NK;                         // [NB]
    unsigned* pay_st   = (unsigned*)(partials + 1024);     // [E]
    float*    pay_n    = (float*)(pay_st + E);             // [E]

    // zero stats + cnt only (adjacent); acc is fully written by aggregate
    hipMemsetAsync(stats, 0, (256 + (size_t)NK) * sizeof(int), stream);

    int eb = (E + 255) / 256;
    hist_kernel<<<eb, 256, 0, stream>>>(dst, cnt, E, V);
    scan_partial_kernel<<<NB, SCAN_BLOCK, 0, stream>>>(cnt, partials, NK);
    scan_top_kernel<<<1, 1024, 0, stream>>>(partials, NB);
    scan_final_kernel<<<NB, SCAN_BLOCK, 0, stream>>>(cnt, partials, off, cur, NK, E);
    rank_kernel<<<eb, 256, 0, stream>>>(dst, src, edge_type, edge_norm,
                                        cur, pay_st, pay_n, E, V);
    aggregate_kernel<<<(NK * 32 + 255) / 256, 256, 0, stream>>>(
        x, rel_repr, pay_st, pay_n, off, acc, NK);

    // fused 3-way GEMM + bias + /3
    fused_gemm_kernel<<<(V + GEMM_ROWS - 1) / GEMM_ROWS, 256, 0, stream>>>(
        acc /*acc_in*/, acc + (size_t)V * 128 /*acc_out*/, x,
        in_w, out_w, loop_w, loop_rel, bias, h, V);

    bn_stats_kernel<<<512, 256, 0, stream>>>(h, stats, V);
    bn_apply_kernel<<<1024, 256, 0, stream>>>(h, stats, bn_gamma, bn_beta, V);
    rel_gemm_kernel<<<(R + 1) / 2, 256, 0, stream>>>(rel_repr, w_rel, out_rel, R);
}

// Round 4
// 238.367 us; speedup vs baseline: 6.3191x; 1.3211x over previous
//
#include <hip/hip_runtime.h>
#include <hip/hip_bf16.h>

// ---------------------------------------------------------------------------
// CompGCN layer:
//   CSR-by-(dst,half) counting sort (3-phase parallel scan), per-bucket
//   register aggregation, bf16-MFMA fused 3-way GEMM + bias + /3,
//   BN(train) + ReLU, out_rel = rel @ w_rel.
// ---------------------------------------------------------------------------

#define SCAN_BLOCK 256

typedef __attribute__((ext_vector_type(8))) short short8v;   // 8 bf16 (4 VGPRs)
typedef __attribute__((ext_vector_type(4))) float float4v;   // MFMA C/D

__device__ inline short f2bf(float f) {
    union { float f; unsigned u; } c; c.f = f;
    unsigned u = c.u;
    return (short)((u + 0x7fffu + ((u >> 16) & 1u)) >> 16);  // RNE
}

__global__ __launch_bounds__(256) void hist_kernel(
    const int* __restrict__ dst, int* __restrict__ cnt, int E, int V)
{
    int e = blockIdx.x * 256 + threadIdx.x;
    if (e >= E) return;
    int key = dst[e] + (e < (E >> 1) ? 0 : V);
    atomicAdd(&cnt[key], 1);
}

// phase 1: per-block sums of 256 counts
__global__ __launch_bounds__(SCAN_BLOCK) void scan_partial_kernel(
    const int* __restrict__ cnt, int* __restrict__ partials, int N)
{
    __shared__ int red[SCAN_BLOCK];
    int i = blockIdx.x * SCAN_BLOCK + threadIdx.x;
    red[threadIdx.x] = (i < N) ? cnt[i] : 0;
    __syncthreads();
    for (int s = SCAN_BLOCK / 2; s > 0; s >>= 1) {
        if (threadIdx.x < s) red[threadIdx.x] += red[threadIdx.x + s];
        __syncthreads();
    }
    if (threadIdx.x == 0) partials[blockIdx.x] = red[0];
}

// phase 2: one block scans the block sums -> exclusive block offsets
__global__ __launch_bounds__(1024) void scan_top_kernel(
    int* __restrict__ partials, int NB)
{
    __shared__ int sh[1024];
    int t = threadIdx.x;
    sh[t] = (t < NB) ? partials[t] : 0;
    __syncthreads();
    for (int s = 1; s < 1024; s <<= 1) {
        int v = (t >= s) ? sh[t - s] : 0;
        __syncthreads();
        sh[t] += v;
        __syncthreads();
    }
    if (t < NB) partials[t] = (t == 0) ? 0 : sh[t - 1];
}

// phase 3: block-local scan + block offset -> off/cur
__global__ __launch_bounds__(SCAN_BLOCK) void scan_final_kernel(
    const int* __restrict__ cnt, const int* __restrict__ partials,
    int* __restrict__ off, int* __restrict__ cur, int N, int E)
{
    __shared__ int sh[SCAN_BLOCK];
    int i = blockIdx.x * SCAN_BLOCK + threadIdx.x;
    int t = threadIdx.x;
    int v = (i < N) ? cnt[i] : 0;
    sh[t] = v;
    __syncthreads();
    for (int s = 1; s < SCAN_BLOCK; s <<= 1) {
        int u = (t >= s) ? sh[t - s] : 0;
        __syncthreads();
        sh[t] += u;
        __syncthreads();
    }
    int excl = partials[blockIdx.x] + sh[t] - v;
    if (i < N) { off[i] = excl; cur[i] = excl; }
    if (i == 0) off[N] = E;
}

// scatter pre-gathered payload into sorted position
__global__ __launch_bounds__(256) void rank_kernel(
    const int* __restrict__ dst,
    const int* __restrict__ src,
    const int* __restrict__ edge_type,
    const float* __restrict__ edge_norm,
    int* __restrict__ cur,
    unsigned* __restrict__ pay_st,   // (src<<16)|type
    float* __restrict__ pay_n,
    int E, int V)
{
    int e = blockIdx.x * 256 + threadIdx.x;
    if (e >= E) return;
    int key = dst[e] + (e < (E >> 1) ? 0 : V);
    int pos = atomicAdd(&cur[key], 1);
    pay_st[pos] = ((unsigned)src[e] << 16) | (unsigned)edge_type[e];
    pay_n[pos]  = edge_norm[e];
}

// one 32-lane group per bucket; plain stores, no feature atomics
__global__ __launch_bounds__(256) void aggregate_kernel(
    const float* __restrict__ x,
    const float* __restrict__ rel,
    const unsigned* __restrict__ pay_st,
    const float* __restrict__ pay_n,
    const int* __restrict__ off,
    float* __restrict__ acc,         // [2V,128] = [acc_in ; acc_out]
    int NK)
{
    int gid = (blockIdx.x * 256 + threadIdx.x) >> 5;
    if (gid >= NK) return;
    int lane = threadIdx.x & 31;
    int f0 = lane << 2;

    int beg = off[gid], end = off[gid + 1];
    float4 a = make_float4(0.f, 0.f, 0.f, 0.f);

    for (int base = beg; base < end; base += 32) {
        int j = base + lane;
        unsigned p = 0; float n = 0.f;
        if (j < end) { p = pay_st[j]; n = pay_n[j]; }
        int m = min(32, end - base);
        for (int q = 0; q < m; ++q) {
            unsigned pq = __shfl(p, q, 32);
            float nq = __shfl(n, q, 32);
            int s = (int)(pq >> 16);
            int t = (int)(pq & 0xffffu);
            const float4 xv = *reinterpret_cast<const float4*>(x + (size_t)s * 128 + f0);
            const float4 rv = *reinterpret_cast<const float4*>(rel + (size_t)t * 128 + f0);
            a.x += xv.x * rv.x * nq;
            a.y += xv.y * rv.y * nq;
            a.z += xv.z * rv.z * nq;
            a.w += xv.w * rv.w * nq;
        }
    }
    *reinterpret_cast<float4*>(acc + (size_t)gid * 128 + f0) = a;
}

// pack in_w/out_w/loop_w into bf16 MFMA B-fragment order:
// wpack[((m*8 + cblk)*4 + t)*64 + lane][j] = bf16( W_m[t*32 + (lane>>4)*8 + j][cblk*16 + (lane&15)] )
__global__ __launch_bounds__(256) void wpack_kernel(
    const float* __restrict__ in_w,
    const float* __restrict__ out_w,
    const float* __restrict__ loop_w,
    short* __restrict__ wpack)
{
    int idx = blockIdx.x * 256 + threadIdx.x;
    if (idx >= 3 * 8 * 4 * 64) return;
    int lane = idx & 63;
    int t    = (idx >> 6) & 3;
    int cblk = (idx >> 8) & 7;
    int m    = idx >> 11;
    const float* W = (m == 0) ? in_w : (m == 1) ? out_w : loop_w;
    int col = cblk * 16 + (lane & 15);
    int kb  = t * 32 + ((lane >> 4) << 3);
    short8v v;
#pragma unroll
    for (int j = 0; j < 8; ++j) v[j] = f2bf(W[(kb + j) * 128 + col]);
    *reinterpret_cast<short8v*>(wpack + (size_t)idx * 8) = v;
}

// bf16 MFMA fused GEMM: h = (acc_in@in_w + acc_out@out_w + (x*loop_rel)@loop_w)/3 + bias
// block = 64 rows x 128 cols, 4 waves (16 rows each), no LDS.
__global__ __launch_bounds__(256) void fused_gemm_mfma_kernel(
    const float* __restrict__ acc,       // [2V,128]
    const float* __restrict__ x,
    const float* __restrict__ loop_rel,
    const short* __restrict__ wpack,
    const float* __restrict__ bias,
    float* __restrict__ h,
    int V)
{
    int wave = threadIdx.x >> 6;
    int lane = threadIdx.x & 63;
    int kgrp = lane >> 4;                 // 0..3
    int row0 = blockIdx.x * 64 + wave * 16;
    int rowl = row0 + (lane & 15);        // this lane's A row
    int rowc = min(rowl, V - 1);          // clamp (stores guarded)

    float4v c[8];
#pragma unroll
    for (int b = 0; b < 8; ++b) c[b] = (float4v)(0.f);

    const float* mats[3] = { acc, acc + (size_t)V * 128, x };

    for (int m = 0; m < 3; ++m) {
        const float* A = mats[m] + (size_t)rowc * 128;
#pragma unroll
        for (int t = 0; t < 4; ++t) {
            int k0 = t * 32 + (kgrp << 3);
            float4 a0 = *reinterpret_cast<const float4*>(A + k0);
            float4 a1 = *reinterpret_cast<const float4*>(A + k0 + 4);
            if (m == 2) {
                float4 l0 = *reinterpret_cast<const float4*>(loop_rel + k0);
                float4 l1 = *reinterpret_cast<const float4*>(loop_rel + k0 + 4);
                a0.x *= l0.x; a0.y *= l0.y; a0.z *= l0.z; a0.w *= l0.w;
                a1.x *= l1.x; a1.y *= l1.y; a1.z *= l1.z; a1.w *= l1.w;
            }
            short8v af;
            af[0] = f2bf(a0.x); af[1] = f2bf(a0.y); af[2] = f2bf(a0.z); af[3] = f2bf(a0.w);
            af[4] = f2bf(a1.x); af[5] = f2bf(a1.y); af[6] = f2bf(a1.z); af[7] = f2bf(a1.w);
            const short* wp = wpack + (((size_t)(m * 8) * 4 + t) * 64 + lane) * 8;
#pragma unroll
            for (int b = 0; b < 8; ++b) {
                short8v bf_ = *reinterpret_cast<const short8v*>(wp + (size_t)b * 4 * 64 * 8);
                c[b] = __builtin_amdgcn_mfma_f32_16x16x32_bf16(af, bf_, c[b], 0, 0, 0);
            }
        }
    }

    // epilogue: C/D layout col=lane&15, row=(lane>>4)*4+r  [m89]
#pragma unroll
    for (int b = 0; b < 8; ++b) {
        int col = b * 16 + (lane & 15);
        float bv = bias[col];
#pragma unroll
        for (int r = 0; r < 4; ++r) {
            int row = row0 + kgrp * 4 + r;
            if (row < V)
                h[(size_t)row * 128 + col] = c[b][r] * (1.f / 3.f) + bv;
        }
    }
}

__global__ __launch_bounds__(256) void bn_stats_kernel(
    const float* __restrict__ h,
    float* __restrict__ stats,   // [0:128] sum, [128:256] sumsq
    int V)
{
    int col = threadIdx.x & 127;
    int rg  = threadIdx.x >> 7;
    float s = 0.f, s2 = 0.f;
    for (int row = blockIdx.x * 2 + rg; row < V; row += gridDim.x * 2) {
        float v = h[(size_t)row * 128 + col];
        s  += v;
        s2 += v * v;
    }
    __shared__ float red[256];
    red[threadIdx.x] = s;
    __syncthreads();
    float s_sum = (rg == 0) ? (s + red[threadIdx.x + 128]) : 0.f;
    __syncthreads();
    red[threadIdx.x] = s2;
    __syncthreads();
    if (rg == 0) {
        float s2_sum = s2 + red[threadIdx.x + 128];
        atomicAdd(&stats[col], s_sum);
        atomicAdd(&stats[128 + col], s2_sum);
    }
}

__global__ __launch_bounds__(256) void bn_apply_kernel(
    float* __restrict__ h,
    const float* __restrict__ stats,
    const float* __restrict__ gamma,
    const float* __restrict__ beta,
    int V)
{
    int col = threadIdx.x & 127;
    int rg  = threadIdx.x >> 7;
    float inv_v = 1.f / (float)V;
    float mean = stats[col] * inv_v;
    float var  = stats[128 + col] * inv_v - mean * mean;
    float sc = rsqrtf(var + 1e-5f) * gamma[col];
    float sh = beta[col] - mean * sc;
    for (int row = blockIdx.x * 2 + rg; row < V; row += gridDim.x * 2) {
        float v = h[(size_t)row * 128 + col];
        v = v * sc + sh;
        h[(size_t)row * 128 + col] = v > 0.f ? v : 0.f;
    }
}

__global__ __launch_bounds__(256) void rel_gemm_kernel(
    const float* __restrict__ rel,
    const float* __restrict__ w_rel,
    float* __restrict__ out_rel,
    int R)
{
    int col = threadIdx.x & 127;
    int row = blockIdx.x * 2 + (threadIdx.x >> 7);
    if (row >= R) return;
    float acc = 0.f;
    for (int k = 0; k < 128; ++k)
        acc += rel[row * 128 + k] * w_rel[k * 128 + col];
    out_rel[row * 128 + col] = acc;
}

extern "C" void kernel_launch(void* const* d_in, const int* in_sizes, int n_in,
                              void* d_out, int out_size, void* d_ws, size_t ws_size,
                              hipStream_t stream)
{
    const float* x         = (const float*)d_in[0];
    const float* rel_repr  = (const float*)d_in[1];
    const float* edge_norm = (const float*)d_in[2];
    const float* in_w      = (const float*)d_in[3];
    const float* out_w     = (const float*)d_in[4];
    const float* loop_w    = (const float*)d_in[5];
    const float* w_rel     = (const float*)d_in[6];
    const float* loop_rel  = (const float*)d_in[7];
    const float* bias      = (const float*)d_in[8];
    const float* bn_gamma  = (const float*)d_in[9];
    const float* bn_beta   = (const float*)d_in[10];
    const int* edge_type   = (const int*)d_in[11];
    const int* src         = (const int*)d_in[12];
    const int* dst         = (const int*)d_in[13];

    const int V = in_sizes[0] / 128;     // 50000
    const int E = in_sizes[2];           // 800000
    const int R = in_sizes[1] / 128;     // 200
    const int NK = 2 * V;                // buckets: [dst(in) ; dst(out)]
    const int NB = (NK + SCAN_BLOCK - 1) / SCAN_BLOCK;   // scan blocks (391)

    float* h       = (float*)d_out;              // [V,128]
    float* out_rel = h + (size_t)V * 128;        // [R,128]

    // workspace layout
    float*    acc      = (float*)d_ws;                     // [2V,128]
    float*    stats    = acc + (size_t)NK * 128;           // [256]
    int*      cnt      = (int*)(stats + 256);              // [2V]
    int*      off      = cnt + NK;                         // [2V+1]
    int*      cur      = off + NK + 1;                     // [2V]
    int*      partials = cur + NK;                         // [1024]
    unsigned* pay_st   = (unsigned*)(partials + 1024);     // [E]
    float*    pay_n    = (float*)(pay_st + E);             // [E]
    short*    wpack    = (short*)(pay_n + E);              // [3*8*4*64*8]

    // zero stats + cnt only (adjacent); acc is fully written by aggregate
    hipMemsetAsync(stats, 0, (256 + (size_t)NK) * sizeof(int), stream);

    wpack_kernel<<<(3 * 8 * 4 * 64 + 255) / 256, 256, 0, stream>>>(
        in_w, out_w, loop_w, wpack);

    int eb = (E + 255) / 256;
    hist_kernel<<<eb, 256, 0, stream>>>(dst, cnt, E, V);
    scan_partial_kernel<<<NB, SCAN_BLOCK, 0, stream>>>(cnt, partials, NK);
    scan_top_kernel<<<1, 1024, 0, stream>>>(partials, NB);
    scan_final_kernel<<<NB, SCAN_BLOCK, 0, stream>>>(cnt, partials, off, cur, NK, E);
    rank_kernel<<<eb, 256, 0, stream>>>(dst, src, edge_type, edge_norm,
                                        cur, pay_st, pay_n, E, V);
    aggregate_kernel<<<(NK * 32 + 255) / 256, 256, 0, stream>>>(
        x, rel_repr, pay_st, pay_n, off, acc, NK);

    // bf16-MFMA fused 3-way GEMM + bias + /3
    fused_gemm_mfma_kernel<<<(V + 63) / 64, 256, 0, stream>>>(
        acc, x, loop_rel, wpack, bias, h, V);

    bn_stats_kernel<<<512, 256, 0, stream>>>(h, stats, V);
    bn_apply_kernel<<<1024, 256, 0, stream>>>(h, stats, bn_gamma, bn_beta, V);
    rel_gemm_kernel<<<(R + 1) / 2, 256, 0, stream>>>(rel_repr, w_rel, out_rel, R);
}

// Round 5
// 218.082 us; speedup vs baseline: 6.9069x; 1.0930x over previous
//
#include <hip/hip_runtime.h>
#include <hip/hip_bf16.h>

// ---------------------------------------------------------------------------
// CompGCN layer:
//   bf16 data plane: x/rel cast once, CSR-by-(dst,half) counting sort,
//   per-bucket register aggregation (bf16 gathers, f32 accum, bf16 acc),
//   bf16-MFMA fused 3-way GEMM (+loop_rel folded into loop_w) + bias + /3,
//   BN(train) + ReLU, out_rel = rel @ w_rel.
// ---------------------------------------------------------------------------

#define SCAN_BLOCK 256

typedef __attribute__((ext_vector_type(8))) short short8v;   // 8 bf16 (4 VGPRs)
typedef __attribute__((ext_vector_type(4))) float float4v;   // MFMA C/D

__device__ inline short f2bf(float f) {
    union { float f; unsigned u; } c; c.f = f;
    unsigned u = c.u;
    return (short)((u + 0x7fffu + ((u >> 16) & 1u)) >> 16);  // RNE
}
__device__ inline float bflo(unsigned u) { return __uint_as_float(u << 16); }
__device__ inline float bfhi(unsigned u) { return __uint_as_float(u & 0xffff0000u); }

// cast x [V,128] and rel [R,128] to bf16, 8 elems/thread
__global__ __launch_bounds__(256) void xcast_kernel(
    const float* __restrict__ x, const float* __restrict__ rel,
    short* __restrict__ xbf, short* __restrict__ relbf, int V, int R)
{
    size_t i = ((size_t)blockIdx.x * 256 + threadIdx.x) * 8;
    size_t nx = (size_t)V * 128;
    size_t total = nx + (size_t)R * 128;
    if (i >= total) return;
    const float* sp; short* dp; size_t k;
    if (i < nx) { sp = x; dp = xbf; k = i; }
    else        { sp = rel; dp = relbf; k = i - nx; }
    float4 v0 = *reinterpret_cast<const float4*>(sp + k);
    float4 v1 = *reinterpret_cast<const float4*>(sp + k + 4);
    short8v o;
    o[0] = f2bf(v0.x); o[1] = f2bf(v0.y); o[2] = f2bf(v0.z); o[3] = f2bf(v0.w);
    o[4] = f2bf(v1.x); o[5] = f2bf(v1.y); o[6] = f2bf(v1.z); o[7] = f2bf(v1.w);
    *reinterpret_cast<short8v*>(dp + k) = o;
}

__global__ __launch_bounds__(256) void hist_kernel(
    const int* __restrict__ dst, int* __restrict__ cnt, int E, int V)
{
    int e = blockIdx.x * 256 + threadIdx.x;
    if (e >= E) return;
    int key = dst[e] + (e < (E >> 1) ? 0 : V);
    atomicAdd(&cnt[key], 1);
}

__global__ __launch_bounds__(SCAN_BLOCK) void scan_partial_kernel(
    const int* __restrict__ cnt, int* __restrict__ partials, int N)
{
    __shared__ int red[SCAN_BLOCK];
    int i = blockIdx.x * SCAN_BLOCK + threadIdx.x;
    red[threadIdx.x] = (i < N) ? cnt[i] : 0;
    __syncthreads();
    for (int s = SCAN_BLOCK / 2; s > 0; s >>= 1) {
        if (threadIdx.x < s) red[threadIdx.x] += red[threadIdx.x + s];
        __syncthreads();
    }
    if (threadIdx.x == 0) partials[blockIdx.x] = red[0];
}

__global__ __launch_bounds__(1024) void scan_top_kernel(
    int* __restrict__ partials, int NB)
{
    __shared__ int sh[1024];
    int t = threadIdx.x;
    sh[t] = (t < NB) ? partials[t] : 0;
    __syncthreads();
    for (int s = 1; s < 1024; s <<= 1) {
        int v = (t >= s) ? sh[t - s] : 0;
        __syncthreads();
        sh[t] += v;
        __syncthreads();
    }
    if (t < NB) partials[t] = (t == 0) ? 0 : sh[t - 1];
}

__global__ __launch_bounds__(SCAN_BLOCK) void scan_final_kernel(
    const int* __restrict__ cnt, const int* __restrict__ partials,
    int* __restrict__ off, int* __restrict__ cur, int N, int E)
{
    __shared__ int sh[SCAN_BLOCK];
    int i = blockIdx.x * SCAN_BLOCK + threadIdx.x;
    int t = threadIdx.x;
    int v = (i < N) ? cnt[i] : 0;
    sh[t] = v;
    __syncthreads();
    for (int s = 1; s < SCAN_BLOCK; s <<= 1) {
        int u = (t >= s) ? sh[t - s] : 0;
        __syncthreads();
        sh[t] += u;
        __syncthreads();
    }
    int excl = partials[blockIdx.x] + sh[t] - v;
    if (i < N) { off[i] = excl; cur[i] = excl; }
    if (i == 0) off[N] = E;
}

// scatter packed payload (src<<16|type, norm-bits) into sorted position
__global__ __launch_bounds__(256) void rank_kernel(
    const int* __restrict__ dst,
    const int* __restrict__ src,
    const int* __restrict__ edge_type,
    const float* __restrict__ edge_norm,
    int* __restrict__ cur,
    uint2* __restrict__ pay,
    int E, int V)
{
    int e = blockIdx.x * 256 + threadIdx.x;
    if (e >= E) return;
    int key = dst[e] + (e < (E >> 1) ? 0 : V);
    int pos = atomicAdd(&cur[key], 1);
    pay[pos] = make_uint2(((unsigned)src[e] << 16) | (unsigned)edge_type[e],
                          __float_as_uint(edge_norm[e]));
}

// one 32-lane group per bucket; bf16 gathers, f32 accum, bf16 store
__global__ __launch_bounds__(256) void aggregate_kernel(
    const short* __restrict__ xbf,
    const short* __restrict__ relbf,
    const uint2* __restrict__ pay,
    const int* __restrict__ off,
    short* __restrict__ accbf,       // [2V,128] = [acc_in ; acc_out]
    int NK)
{
    int gid = (blockIdx.x * 256 + threadIdx.x) >> 5;
    if (gid >= NK) return;
    int lane = threadIdx.x & 31;
    int f0 = lane << 2;

    int beg = off[gid], end = off[gid + 1];
    float a0 = 0.f, a1 = 0.f, a2 = 0.f, a3 = 0.f;

    for (int base = beg; base < end; base += 32) {
        int j = base + lane;
        uint2 p = (j < end) ? pay[j] : make_uint2(0u, 0u);
        int m = min(32, end - base);
        for (int q = 0; q < m; ++q) {
            unsigned pq = __shfl(p.x, q, 32);
            float nq = __uint_as_float(__shfl(p.y, q, 32));
            int s = (int)(pq >> 16);
            int t = (int)(pq & 0xffffu);
            uint2 xv = *reinterpret_cast<const uint2*>(xbf + (size_t)s * 128 + f0);
            uint2 rv = *reinterpret_cast<const uint2*>(relbf + (size_t)t * 128 + f0);
            a0 += bflo(xv.x) * bflo(rv.x) * nq;
            a1 += bfhi(xv.x) * bfhi(rv.x) * nq;
            a2 += bflo(xv.y) * bflo(rv.y) * nq;
            a3 += bfhi(xv.y) * bfhi(rv.y) * nq;
        }
    }
    uint2 o;
    o.x = (unsigned)(unsigned short)f2bf(a0) | ((unsigned)(unsigned short)f2bf(a1) << 16);
    o.y = (unsigned)(unsigned short)f2bf(a2) | ((unsigned)(unsigned short)f2bf(a3) << 16);
    *reinterpret_cast<uint2*>(accbf + (size_t)gid * 128 + f0) = o;
}

// pack weights into bf16 MFMA B-fragment order; loop_rel folded into loop_w:
// wpack[((m*8 + cblk)*4 + t)*64 + lane][j] = bf16( W'_m[t*32+(lane>>4)*8+j][cblk*16+(lane&15)] )
__global__ __launch_bounds__(256) void wpack_kernel(
    const float* __restrict__ in_w,
    const float* __restrict__ out_w,
    const float* __restrict__ loop_w,
    const float* __restrict__ loop_rel,
    short* __restrict__ wpack)
{
    int idx = blockIdx.x * 256 + threadIdx.x;
    if (idx >= 3 * 8 * 4 * 64) return;
    int lane = idx & 63;
    int t    = (idx >> 6) & 3;
    int cblk = (idx >> 8) & 7;
    int m    = idx >> 11;
    const float* W = (m == 0) ? in_w : (m == 1) ? out_w : loop_w;
    int col = cblk * 16 + (lane & 15);
    int kb  = t * 32 + ((lane >> 4) << 3);
    short8v v;
#pragma unroll
    for (int j = 0; j < 8; ++j) {
        float w = W[(kb + j) * 128 + col];
        if (m == 2) w *= loop_rel[kb + j];
        v[j] = f2bf(w);
    }
    *reinterpret_cast<short8v*>(wpack + (size_t)idx * 8) = v;
}

// bf16 MFMA fused GEMM: h = (acc_in@in_w + acc_out@out_w + x@loop_w')/3 + bias
// block = 64 rows x 128 cols, 4 waves (16 rows each), no LDS, A-frags direct.
__global__ __launch_bounds__(256) void fused_gemm_mfma_kernel(
    const short* __restrict__ accbf,     // [2V,128]
    const short* __restrict__ xbf,       // [V,128]
    const short* __restrict__ wpack,
    const float* __restrict__ bias,
    float* __restrict__ h,
    int V)
{
    int wave = threadIdx.x >> 6;
    int lane = threadIdx.x & 63;
    int kgrp = lane >> 4;                 // 0..3
    int row0 = blockIdx.x * 64 + wave * 16;
    int rowl = row0 + (lane & 15);
    int rowc = min(rowl, V - 1);          // clamp (stores guarded)

    float4v c[8];
#pragma unroll
    for (int b = 0; b < 8; ++b) c[b] = (float4v)(0.f);

    const short* mats[3] = { accbf, accbf + (size_t)V * 128, xbf };

    for (int m = 0; m < 3; ++m) {
        const short* A = mats[m] + (size_t)rowc * 128;
#pragma unroll
        for (int t = 0; t < 4; ++t) {
            short8v af = *reinterpret_cast<const short8v*>(A + t * 32 + (kgrp << 3));
            const short* wp = wpack + (((size_t)(m * 8) * 4 + t) * 64 + lane) * 8;
#pragma unroll
            for (int b = 0; b < 8; ++b) {
                short8v bf_ = *reinterpret_cast<const short8v*>(wp + (size_t)b * 4 * 64 * 8);
                c[b] = __builtin_amdgcn_mfma_f32_16x16x32_bf16(af, bf_, c[b], 0, 0, 0);
            }
        }
    }

    // epilogue: C/D layout col=lane&15, row=(lane>>4)*4+r  [m89]
#pragma unroll
    for (int b = 0; b < 8; ++b) {
        int col = b * 16 + (lane & 15);
        float bv = bias[col];
#pragma unroll
        for (int r = 0; r < 4; ++r) {
            int row = row0 + kgrp * 4 + r;
            if (row < V)
                h[(size_t)row * 128 + col] = c[b][r] * (1.f / 3.f) + bv;
        }
    }
}

__global__ __launch_bounds__(256) void bn_stats_kernel(
    const float* __restrict__ h,
    float* __restrict__ stats,   // [0:128] sum, [128:256] sumsq
    int V)
{
    int col = threadIdx.x & 127;
    int rg  = threadIdx.x >> 7;
    float s = 0.f, s2 = 0.f;
    for (int row = blockIdx.x * 2 + rg; row < V; row += gridDim.x * 2) {
        float v = h[(size_t)row * 128 + col];
        s  += v;
        s2 += v * v;
    }
    __shared__ float red[256];
    red[threadIdx.x] = s;
    __syncthreads();
    float s_sum = (rg == 0) ? (s + red[threadIdx.x + 128]) : 0.f;
    __syncthreads();
    red[threadIdx.x] = s2;
    __syncthreads();
    if (rg == 0) {
        float s2_sum = s2 + red[threadIdx.x + 128];
        atomicAdd(&stats[col], s_sum);
        atomicAdd(&stats[128 + col], s2_sum);
    }
}

__global__ __launch_bounds__(256) void bn_apply_kernel(
    float* __restrict__ h,
    const float* __restrict__ stats,
    const float* __restrict__ gamma,
    const float* __restrict__ beta,
    int V)
{
    int col = threadIdx.x & 127;
    int rg  = threadIdx.x >> 7;
    float inv_v = 1.f / (float)V;
    float mean = stats[col] * inv_v;
    float var  = stats[128 + col] * inv_v - mean * mean;
    float sc = rsqrtf(var + 1e-5f) * gamma[col];
    float sh = beta[col] - mean * sc;
    for (int row = blockIdx.x * 2 + rg; row < V; row += gridDim.x * 2) {
        float v = h[(size_t)row * 128 + col];
        v = v * sc + sh;
        h[(size_t)row * 128 + col] = v > 0.f ? v : 0.f;
    }
}

__global__ __launch_bounds__(256) void rel_gemm_kernel(
    const float* __restrict__ rel,
    const float* __restrict__ w_rel,
    float* __restrict__ out_rel,
    int R)
{
    int col = threadIdx.x & 127;
    int row = blockIdx.x * 2 + (threadIdx.x >> 7);
    if (row >= R) return;
    float acc = 0.f;
    for (int k = 0; k < 128; ++k)
        acc += rel[row * 128 + k] * w_rel[k * 128 + col];
    out_rel[row * 128 + col] = acc;
}

extern "C" void kernel_launch(void* const* d_in, const int* in_sizes, int n_in,
                              void* d_out, int out_size, void* d_ws, size_t ws_size,
                              hipStream_t stream)
{
    const float* x         = (const float*)d_in[0];
    const float* rel_repr  = (const float*)d_in[1];
    const float* edge_norm = (const float*)d_in[2];
    const float* in_w      = (const float*)d_in[3];
    const float* out_w     = (const float*)d_in[4];
    const float* loop_w    = (const float*)d_in[5];
    const float* w_rel     = (const float*)d_in[6];
    const float* loop_rel  = (const float*)d_in[7];
    const float* bias      = (const float*)d_in[8];
    const float* bn_gamma  = (const float*)d_in[9];
    const float* bn_beta   = (const float*)d_in[10];
    const int* edge_type   = (const int*)d_in[11];
    const int* src         = (const int*)d_in[12];
    const int* dst         = (const int*)d_in[13];

    const int V = in_sizes[0] / 128;     // 50000
    const int E = in_sizes[2];           // 800000
    const int R = in_sizes[1] / 128;     // 200
    const int NK = 2 * V;                // buckets: [dst(in) ; dst(out)]
    const int NB = (NK + SCAN_BLOCK - 1) / SCAN_BLOCK;

    float* h       = (float*)d_out;              // [V,128]
    float* out_rel = h + (size_t)V * 128;        // [R,128]

    // workspace layout (manual, 16B-aligned where vector-loaded)
    char* wp_ = (char*)d_ws;
    short* accbf   = (short*)wp_;  wp_ += (size_t)NK * 128 * sizeof(short);
    short* xbf     = (short*)wp_;  wp_ += (size_t)V * 128 * sizeof(short);
    short* relbf   = (short*)wp_;  wp_ += (size_t)R * 128 * sizeof(short);
    short* wpack   = (short*)wp_;  wp_ += (size_t)3 * 8 * 4 * 64 * 8 * sizeof(short);
    float* stats   = (float*)wp_;  wp_ += 256 * sizeof(float);
    int*   cnt     = (int*)wp_;    wp_ += (size_t)NK * sizeof(int);
    int*   off     = (int*)wp_;    wp_ += ((size_t)NK + 1) * sizeof(int);
    int*   cur     = (int*)wp_;    wp_ += (size_t)NK * sizeof(int);
    int*   partials= (int*)wp_;    wp_ += 1024 * sizeof(int);
    wp_ = (char*)(((uintptr_t)wp_ + 15) & ~(uintptr_t)15);
    uint2* pay     = (uint2*)wp_;

    // zero stats + cnt (adjacent); accbf fully written by aggregate
    hipMemsetAsync(stats, 0, 256 * sizeof(float) + (size_t)NK * sizeof(int), stream);

    {
        size_t total = ((size_t)(V + R) * 128) / 8;
        xcast_kernel<<<(int)((total + 255) / 256), 256, 0, stream>>>(
            x, rel_repr, xbf, relbf, V, R);
    }
    wpack_kernel<<<(3 * 8 * 4 * 64 + 255) / 256, 256, 0, stream>>>(
        in_w, out_w, loop_w, loop_rel, wpack);

    int eb = (E + 255) / 256;
    hist_kernel<<<eb, 256, 0, stream>>>(dst, cnt, E, V);
    scan_partial_kernel<<<NB, SCAN_BLOCK, 0, stream>>>(cnt, partials, NK);
    scan_top_kernel<<<1, 1024, 0, stream>>>(partials, NB);
    scan_final_kernel<<<NB, SCAN_BLOCK, 0, stream>>>(cnt, partials, off, cur, NK, E);
    rank_kernel<<<eb, 256, 0, stream>>>(dst, src, edge_type, edge_norm, cur, pay, E, V);
    aggregate_kernel<<<(NK * 32 + 255) / 256, 256, 0, stream>>>(
        xbf, relbf, pay, off, accbf, NK);

    fused_gemm_mfma_kernel<<<(V + 63) / 64, 256, 0, stream>>>(
        accbf, xbf, wpack, bias, h, V);

    bn_stats_kernel<<<512, 256, 0, stream>>>(h, stats, V);
    bn_apply_kernel<<<1024, 256, 0, stream>>>(h, stats, bn_gamma, bn_beta, V);
    rel_gemm_kernel<<<(R + 1) / 2, 256, 0, stream>>>(rel_repr, w_rel, out_rel, R);
}